// Round 3
// baseline (548.490 us; speedup 1.0000x reference)
//
#include <hip/hip_runtime.h>

typedef __bf16 bf16x8 __attribute__((ext_vector_type(8)));
typedef float f32x4 __attribute__((ext_vector_type(4)));

#define LN_EPS 1e-5f

// -------- weight transpose + downcast: in f32 [R][C] -> out bf16 [C][R] --------
__global__ __launch_bounds__(256) void transpose_k(const float* __restrict__ in,
                                                   __bf16* __restrict__ out,
                                                   int R, int C) {
  __shared__ __bf16 t[32][33];
  int tx = threadIdx.x & 31, ty = threadIdx.x >> 5;  // 32x8
  int c = blockIdx.x * 32 + tx;
  for (int j = 0; j < 4; j++) {
    int r = blockIdx.y * 32 + ty + j * 8;
    t[ty + j * 8][tx] = (__bf16)in[(size_t)r * C + c];
  }
  __syncthreads();
  int r2 = blockIdx.y * 32 + tx;
  for (int j = 0; j < 4; j++) {
    int c2 = blockIdx.x * 32 + ty + j * 8;
    out[(size_t)c2 * R + r2] = t[tx][ty + j * 8];
  }
}

// -------- layernorm over 768: f32 in -> bf16 out, one block per row --------
__global__ __launch_bounds__(256) void ln_kernel(const float* __restrict__ x,
                                                 const float* __restrict__ g,
                                                 const float* __restrict__ bta,
                                                 __bf16* __restrict__ out) {
  int row = blockIdx.x;
  size_t base = (size_t)row * 768;
  int t = threadIdx.x;
  float v[3];
  float s = 0.f, s2 = 0.f;
  for (int k = 0; k < 3; k++) {
    float f = x[base + t + k * 256];
    v[k] = f;
    s += f;
    s2 += f * f;
  }
  for (int m = 1; m < 64; m <<= 1) {
    s += __shfl_xor(s, m, 64);
    s2 += __shfl_xor(s2, m, 64);
  }
  __shared__ float sm[4][2];
  int wid = t >> 6, lane = t & 63;
  if (lane == 0) { sm[wid][0] = s; sm[wid][1] = s2; }
  __syncthreads();
  s = sm[0][0] + sm[1][0] + sm[2][0] + sm[3][0];
  s2 = sm[0][1] + sm[1][1] + sm[2][1] + sm[3][1];
  float mu = s * (1.f / 768.f);
  float var = s2 * (1.f / 768.f) - mu * mu;
  float rstd = rsqrtf(var + LN_EPS);
  for (int k = 0; k < 3; k++) {
    int c = t + k * 256;
    out[base + c] = (__bf16)((v[k] - mu) * rstd * g[c] + bta[c]);
  }
}

// -------- MFMA GEMM: C[M,N] = A[M,K] @ BT[N,K]^T + bias --------
// EPI 0: bf16 out = c                                   (qkv)
// EPI 1: bf16 out = gelu_a*c^2 + gelu_b*c + gelu_c      (fc1 + PolyGELU)
// EPI 2: f32  out = c + res_f32                         (proj+res -> x1, fc2+res -> d_out)
template <int EPI>
__global__ __launch_bounds__(256) void gemm128(const __bf16* __restrict__ A,
                                               const __bf16* __restrict__ BT,
                                               const float* __restrict__ bias,
                                               const float* __restrict__ res,
                                               void* __restrict__ outv,
                                               int M, int N, int K,
                                               const float* __restrict__ c0p,
                                               const float* __restrict__ c1p,
                                               const float* __restrict__ c2p) {
  __shared__ __bf16 As[128][40];  // pad 8: row stride 80B (16B aligned)
  __shared__ __bf16 Bs[128][40];
  int tid = threadIdx.x;
  int lane = tid & 63, wid = tid >> 6;
  int wr = wid >> 1, wc = wid & 1;  // 2x2 waves of 64x64
  int m0 = blockIdx.y * 128, n0 = blockIdx.x * 128;
  int mr = lane & 15, kq = (lane >> 4) * 8;

  f32x4 acc[4][4] = {};

  for (int k0 = 0; k0 < K; k0 += 32) {
    for (int i = 0; i < 2; i++) {
      int chunk = tid + i * 256;
      int row = chunk >> 2, kc = chunk & 3;
      *(bf16x8*)&As[row][kc * 8] =
          *(const bf16x8*)&A[(size_t)(m0 + row) * K + k0 + kc * 8];
      *(bf16x8*)&Bs[row][kc * 8] =
          *(const bf16x8*)&BT[(size_t)(n0 + row) * K + k0 + kc * 8];
    }
    __syncthreads();
    bf16x8 af[4], bfr[4];
    for (int i = 0; i < 4; i++) af[i] = *(bf16x8*)&As[wr * 64 + i * 16 + mr][kq];
    for (int j = 0; j < 4; j++) bfr[j] = *(bf16x8*)&Bs[wc * 64 + j * 16 + mr][kq];
    for (int i = 0; i < 4; i++)
      for (int j = 0; j < 4; j++)
        acc[i][j] = __builtin_amdgcn_mfma_f32_16x16x32_bf16(af[i], bfr[j], acc[i][j], 0, 0, 0);
    __syncthreads();
  }

  float ga = 0.f, gb = 0.f, gc = 0.f;
  if (EPI == 1) { ga = *c0p; gb = *c1p; gc = *c2p; }

  for (int i = 0; i < 4; i++) {
    for (int j = 0; j < 4; j++) {
      int col = n0 + wc * 64 + j * 16 + mr;
      float bv = bias[col];
      for (int r = 0; r < 4; r++) {
        int row = m0 + wr * 64 + i * 16 + (lane >> 4) * 4 + r;
        size_t idx = (size_t)row * N + col;
        float c = acc[i][j][r] + bv;
        if (EPI == 0) {
          ((__bf16*)outv)[idx] = (__bf16)c;
        } else if (EPI == 1) {
          float u = (ga * c + gb) * c + gc;
          ((__bf16*)outv)[idx] = (__bf16)u;
        } else {
          ((float*)outv)[idx] = c + res[idx];
        }
      }
    }
  }
}

// -------- flash-style polynomial attention --------
// qkv: [B*N, 2304] bf16 (q|k|v each 768 = 12 heads * 64)
// out: [B*N, 768] bf16, token-major [b,n,h*64+d]
__global__ __launch_bounds__(256) void attn_poly(const __bf16* __restrict__ qkv,
                                                 __bf16* __restrict__ outp,
                                                 const float* __restrict__ ap,
                                                 const float* __restrict__ bp,
                                                 const float* __restrict__ cp) {
  __shared__ __bf16 Qs[128][72];     // pad to 72: 144B row stride, 16B aligned
  __shared__ __bf16 Ks[64][72];
  __shared__ __bf16 Vt[64][72];      // transposed: Vt[d][key]
  __shared__ __bf16 Ps[4][32][72];   // per-wave P tile (C-layout -> A-layout round trip)

  int tid = threadIdx.x, lane = tid & 63, wid = tid >> 6;
  int mr = lane & 15, kq = (lane >> 4) * 8;
  int q0 = blockIdx.x * 128;
  int h = blockIdx.y, b = blockIdx.z;
  size_t baseQ = ((size_t)b * 2048) * 2304 + h * 64;

  for (int i = 0; i < 4; i++) {
    int chunk = tid + i * 256;
    int row = chunk >> 3, dc = chunk & 7;
    *(bf16x8*)&Qs[row][dc * 8] =
        *(const bf16x8*)&qkv[baseQ + (size_t)(q0 + row) * 2304 + dc * 8];
  }
  __syncthreads();

  bf16x8 qf[2][2];
  for (int i = 0; i < 2; i++)
    for (int s = 0; s < 2; s++)
      qf[i][s] = *(bf16x8*)&Qs[wid * 32 + i * 16 + mr][s * 32 + kq];

  float aa = *ap, ab = *bp, ac = *cp;
  f32x4 o_acc[2][4] = {};
  float l_acc[2][4] = {{0.f, 0.f, 0.f, 0.f}, {0.f, 0.f, 0.f, 0.f}};

  for (int kt = 0; kt < 32; kt++) {
    __syncthreads();  // protect Ks/Vt/Ps before restaging
    for (int i = 0; i < 2; i++) {
      int chunk = tid + i * 256;
      int row = chunk >> 3, dc = chunk & 7;
      size_t gidx = baseQ + (size_t)(kt * 64 + row) * 2304 + dc * 8;
      *(bf16x8*)&Ks[row][dc * 8] = *(const bf16x8*)&qkv[gidx + 768];
      bf16x8 vv = *(const bf16x8*)&qkv[gidx + 1536];
      for (int e = 0; e < 8; e++) Vt[dc * 8 + e][row] = vv[e];
    }
    __syncthreads();  // staging done

    // S = Q K^T, poly, row-sum, P -> LDS (per wave: 32 q-rows x 64 keys)
    for (int i = 0; i < 2; i++) {
      f32x4 sacc[4] = {};
      for (int j = 0; j < 4; j++) {
        for (int s = 0; s < 2; s++) {
          bf16x8 kf = *(bf16x8*)&Ks[j * 16 + mr][s * 32 + kq];
          sacc[j] = __builtin_amdgcn_mfma_f32_16x16x32_bf16(qf[i][s], kf, sacc[j], 0, 0, 0);
        }
      }
      float rs[4] = {0.f, 0.f, 0.f, 0.f};
      for (int j = 0; j < 4; j++) {
        for (int r = 0; r < 4; r++) {
          float S = sacc[j][r] * 0.125f;             // * HEAD_DIM^-0.5
          float p = fmaf(fmaf(aa, S, ab), S, ac);    // a*S^2 + b*S + c
          p = fmaxf(p, 1e-6f);
          rs[r] += p;
          Ps[wid][i * 16 + (lane >> 4) * 4 + r][j * 16 + mr] = (__bf16)p;
        }
      }
      for (int r = 0; r < 4; r++) {
        float v = rs[r];
        v += __shfl_xor(v, 1, 16);
        v += __shfl_xor(v, 2, 16);
        v += __shfl_xor(v, 4, 16);
        v += __shfl_xor(v, 8, 16);
        l_acc[i][r] += v;
      }
    }

    // cross-lane LDS dependency (C-layout writes -> A-layout reads)
    __syncthreads();

    // O += P @ V
    for (int i = 0; i < 2; i++) {
      for (int s = 0; s < 2; s++) {
        bf16x8 pf = *(bf16x8*)&Ps[wid][i * 16 + mr][s * 32 + kq];
        for (int jd = 0; jd < 4; jd++) {
          bf16x8 vf = *(bf16x8*)&Vt[jd * 16 + mr][s * 32 + kq];
          o_acc[i][jd] = __builtin_amdgcn_mfma_f32_16x16x32_bf16(pf, vf, o_acc[i][jd], 0, 0, 0);
        }
      }
    }
  }

  size_t baseO = ((size_t)b * 2048) * 768 + h * 64;
  for (int i = 0; i < 2; i++) {
    for (int r = 0; r < 4; r++) {
      float inv = 1.0f / (l_acc[i][r] + 1e-8f);
      int q = q0 + wid * 32 + i * 16 + (lane >> 4) * 4 + r;
      for (int jd = 0; jd < 4; jd++) {
        int d = jd * 16 + mr;
        outp[baseO + (size_t)q * 768 + d] = (__bf16)(o_acc[i][jd][r] * inv);
      }
    }
  }
}

extern "C" void kernel_launch(void* const* d_in, const int* in_sizes, int n_in,
                              void* d_out, int out_size, void* d_ws, size_t ws_size,
                              hipStream_t stream) {
  // ALL reference dtypes are float32
  const float* x     = (const float*)d_in[0];
  const float* ln1g  = (const float*)d_in[1];
  const float* ln1b  = (const float*)d_in[2];
  const float* ln2g  = (const float*)d_in[3];
  const float* ln2b  = (const float*)d_in[4];
  const float* qkvw  = (const float*)d_in[5];
  const float* qkvb  = (const float*)d_in[6];
  const float* projw = (const float*)d_in[7];
  const float* projb = (const float*)d_in[8];
  const float* fc1w  = (const float*)d_in[9];
  const float* fc1b  = (const float*)d_in[10];
  const float* fc2w  = (const float*)d_in[11];
  const float* fc2b  = (const float*)d_in[12];
  const float* attna = (const float*)d_in[13];
  const float* attnb = (const float*)d_in[14];
  const float* attnc = (const float*)d_in[15];
  const float* gelua = (const float*)d_in[16];
  const float* gelub = (const float*)d_in[17];
  const float* geluc = (const float*)d_in[18];

  char* ws = (char*)d_ws;
  // layout (peak 102,236,160 B), all offsets 16B-aligned:
  __bf16* wT_qkv  = (__bf16*)(ws);             // [2304][768]  3,538,944 B
  __bf16* wT_proj = (__bf16*)(ws + 3538944);   // [768][768]   1,179,648 B
  __bf16* wT_fc1  = (__bf16*)(ws + 4718592);   // [3072][768]  4,718,592 B
  __bf16* wT_fc2  = (__bf16*)(ws + 9437184);   // [768][3072]  4,718,592 B
  __bf16* h       = (__bf16*)(ws + 14155776);  // [8192][768]  bf16 12,582,912 B
  float*  x1      = (float*)(ws + 26738688);   // [8192][768]  f32  25,165,824 B
  __bf16* qkvbuf  = (__bf16*)(ws + 51904512);  // [8192][2304] bf16 37,748,736 B (dead after attn)
  __bf16* u       = (__bf16*)(ws + 51904512);  // [8192][3072] bf16 50,331,648 B (overlaps qkv)
  float*  outp    = (float*)d_out;

  // weight transposes + downcast
  transpose_k<<<dim3(2304 / 32, 768 / 32), 256, 0, stream>>>(qkvw, wT_qkv, 768, 2304);
  transpose_k<<<dim3(768 / 32, 768 / 32), 256, 0, stream>>>(projw, wT_proj, 768, 768);
  transpose_k<<<dim3(3072 / 32, 768 / 32), 256, 0, stream>>>(fc1w, wT_fc1, 768, 3072);
  transpose_k<<<dim3(768 / 32, 3072 / 32), 256, 0, stream>>>(fc2w, wT_fc2, 3072, 768);

  // attention branch
  ln_kernel<<<8192, 256, 0, stream>>>(x, ln1g, ln1b, h);
  gemm128<0><<<dim3(18, 64), 256, 0, stream>>>(h, wT_qkv, qkvb, nullptr, qkvbuf,
                                               8192, 2304, 768, nullptr, nullptr, nullptr);
  attn_poly<<<dim3(16, 12, 4), 256, 0, stream>>>(qkvbuf, h, attna, attnb, attnc);
  gemm128<2><<<dim3(6, 64), 256, 0, stream>>>(h, wT_proj, projb, x, x1,
                                              8192, 768, 768, nullptr, nullptr, nullptr);
  // MLP branch
  ln_kernel<<<8192, 256, 0, stream>>>(x1, ln2g, ln2b, h);
  gemm128<1><<<dim3(24, 64), 256, 0, stream>>>(h, wT_fc1, fc1b, nullptr, u,
                                               8192, 3072, 768, gelua, gelub, geluc);
  gemm128<2><<<dim3(6, 64), 256, 0, stream>>>(u, wT_fc2, fc2b, x1, outp,
                                              8192, 768, 3072, nullptr, nullptr, nullptr);
}

// Round 4
// 491.182 us; speedup vs baseline: 1.1167x; 1.1167x over previous
//
#include <hip/hip_runtime.h>

typedef __bf16 bf16x8 __attribute__((ext_vector_type(8)));
typedef float f32x4 __attribute__((ext_vector_type(4)));

#define LN_EPS 1e-5f

// async global->LDS, 16B per lane (wave-uniform LDS base + lane*16)
__device__ __forceinline__ void gl2lds16(const void* g, void* l) {
  __builtin_amdgcn_global_load_lds(
      (const __attribute__((address_space(1))) unsigned int*)g,
      (__attribute__((address_space(3))) unsigned int*)l, 16, 0, 0);
}

// -------- weight transpose + downcast: in f32 [R][C] -> out bf16 [C][R] --------
__global__ __launch_bounds__(256) void transpose_k(const float* __restrict__ in,
                                                   __bf16* __restrict__ out,
                                                   int R, int C) {
  __shared__ __bf16 t[32][33];
  int tx = threadIdx.x & 31, ty = threadIdx.x >> 5;  // 32x8
  int c = blockIdx.x * 32 + tx;
  for (int j = 0; j < 4; j++) {
    int r = blockIdx.y * 32 + ty + j * 8;
    t[ty + j * 8][tx] = (__bf16)in[(size_t)r * C + c];
  }
  __syncthreads();
  int r2 = blockIdx.y * 32 + tx;
  for (int j = 0; j < 4; j++) {
    int c2 = blockIdx.x * 32 + ty + j * 8;
    out[(size_t)c2 * R + r2] = t[tx][ty + j * 8];
  }
}

// -------- V transpose: qkv[token][2304] V-part -> vt[(b*12+h)*64+d][2048] --------
__global__ __launch_bounds__(256) void transpose_v(const __bf16* __restrict__ qkv,
                                                   __bf16* __restrict__ vt) {
  __shared__ __bf16 t[32][33];
  int bh = blockIdx.z;
  int b = bh / 12, h = bh % 12;
  int n0 = blockIdx.x * 32, d0 = blockIdx.y * 32;
  int tx = threadIdx.x & 31, ty = threadIdx.x >> 5;
  for (int j = 0; j < 4; j++) {
    int n = n0 + ty + j * 8;
    t[ty + j * 8][tx] = qkv[(size_t)(b * 2048 + n) * 2304 + 1536 + h * 64 + d0 + tx];
  }
  __syncthreads();
  for (int j = 0; j < 4; j++) {
    int d = d0 + ty + j * 8;
    vt[((size_t)bh * 64 + d) * 2048 + n0 + tx] = t[tx][ty + j * 8];
  }
}

// -------- layernorm over 768: f32 in -> bf16 out, one block per row --------
__global__ __launch_bounds__(256) void ln_kernel(const float* __restrict__ x,
                                                 const float* __restrict__ g,
                                                 const float* __restrict__ bta,
                                                 __bf16* __restrict__ out) {
  int row = blockIdx.x;
  size_t base = (size_t)row * 768;
  int t = threadIdx.x;
  float v[3];
  float s = 0.f, s2 = 0.f;
  for (int k = 0; k < 3; k++) {
    float f = x[base + t + k * 256];
    v[k] = f;
    s += f;
    s2 += f * f;
  }
  for (int m = 1; m < 64; m <<= 1) {
    s += __shfl_xor(s, m, 64);
    s2 += __shfl_xor(s2, m, 64);
  }
  __shared__ float sm[4][2];
  int wid = t >> 6, lane = t & 63;
  if (lane == 0) { sm[wid][0] = s; sm[wid][1] = s2; }
  __syncthreads();
  s = sm[0][0] + sm[1][0] + sm[2][0] + sm[3][0];
  s2 = sm[0][1] + sm[1][1] + sm[2][1] + sm[3][1];
  float mu = s * (1.f / 768.f);
  float var = s2 * (1.f / 768.f) - mu * mu;
  float rstd = rsqrtf(var + LN_EPS);
  for (int k = 0; k < 3; k++) {
    int c = t + k * 256;
    out[base + c] = (__bf16)((v[k] - mu) * rstd * g[c] + bta[c]);
  }
}

// -------- MFMA GEMM (m97 structure): C[M,N] = A[M,K] @ BT[N,K]^T + bias --------
// EPI 0: bf16 out = c                                   (qkv)
// EPI 1: bf16 out = gelu_a*c^2 + gelu_b*c + gelu_c      (fc1 + PolyGELU)
// EPI 2: f32  out = c + res_f32                         (proj+res -> x1, fc2+res -> d_out)
template <int EPI>
__global__ __launch_bounds__(256) void gemm128(const __bf16* __restrict__ A,
                                               const __bf16* __restrict__ BT,
                                               const float* __restrict__ bias,
                                               const float* __restrict__ res,
                                               void* __restrict__ outv,
                                               int M, int N, int K,
                                               const float* __restrict__ c0p,
                                               const float* __restrict__ c1p,
                                               const float* __restrict__ c2p) {
  __shared__ __bf16 As[128][32];  // UNPADDED: required by global_load_lds lane mapping
  __shared__ __bf16 Bs[128][32];
  int tid = threadIdx.x;
  int lane = tid & 63, wid = tid >> 6;
  int wr = wid >> 1, wc = wid & 1;  // 2x2 waves of 64x64
  int m0 = blockIdx.y * 128, n0 = blockIdx.x * 128;
  int mr = lane & 15, kq = (lane >> 4) * 8;
  int srow = tid >> 2, scol = (tid & 3) * 8;  // staging: 4 lanes x 16B per row

  f32x4 acc[4][4] = {};

  for (int k0 = 0; k0 < K; k0 += 32) {
    for (int i = 0; i < 2; i++) {
      int row = srow + i * 64;
      gl2lds16(&A[(size_t)(m0 + row) * K + k0 + scol], &As[row][scol]);
      gl2lds16(&BT[(size_t)(n0 + row) * K + k0 + scol], &Bs[row][scol]);
    }
    __syncthreads();  // drains vmcnt (global_load_lds) per compiler semantics
    bf16x8 af[4], bfr[4];
    for (int i = 0; i < 4; i++) af[i] = *(bf16x8*)&As[wr * 64 + i * 16 + mr][kq];
    for (int j = 0; j < 4; j++) bfr[j] = *(bf16x8*)&Bs[wc * 64 + j * 16 + mr][kq];
    for (int i = 0; i < 4; i++)
      for (int j = 0; j < 4; j++)
        acc[i][j] = __builtin_amdgcn_mfma_f32_16x16x32_bf16(af[i], bfr[j], acc[i][j], 0, 0, 0);
    __syncthreads();
  }

  float ga = 0.f, gb = 0.f, gc = 0.f;
  if (EPI == 1) { ga = *c0p; gb = *c1p; gc = *c2p; }

  for (int i = 0; i < 4; i++) {
    for (int j = 0; j < 4; j++) {
      int col = n0 + wc * 64 + j * 16 + mr;
      float bv = bias[col];
      for (int r = 0; r < 4; r++) {
        int row = m0 + wr * 64 + i * 16 + (lane >> 4) * 4 + r;
        size_t idx = (size_t)row * N + col;
        float c = acc[i][j][r] + bv;
        if (EPI == 0) {
          ((__bf16*)outv)[idx] = (__bf16)c;
        } else if (EPI == 1) {
          float u = (ga * c + gb) * c + gc;
          ((__bf16*)outv)[idx] = (__bf16)u;
        } else {
          ((float*)outv)[idx] = c + res[idx];
        }
      }
    }
  }
}

// -------- flash-style polynomial attention (V^T precomputed in global) --------
// qkv: [B*N,2304] bf16 (q|k at cols 0..1535); vt: [(b*12+h)*64+d][2048] bf16
// out: [B*N,768] bf16 token-major
__global__ __launch_bounds__(256) void attn_poly(const __bf16* __restrict__ qkv,
                                                 const __bf16* __restrict__ vt,
                                                 __bf16* __restrict__ outp,
                                                 const float* __restrict__ ap,
                                                 const float* __restrict__ bp,
                                                 const float* __restrict__ cp) {
  // Qs ([128][72]) aliases Ps ([4][32][72]) — Qs is dead after register hoist
  __shared__ __bf16 QPs[4][32][72];
  __shared__ __bf16 Ks[64][72];
  __shared__ __bf16 Vts[64][72];
  __bf16(*Qs)[72] = (__bf16(*)[72]) & QPs[0][0][0];

  int tid = threadIdx.x, lane = tid & 63, wid = tid >> 6;
  int mr = lane & 15, kq = (lane >> 4) * 8;
  int q0 = blockIdx.x * 128;
  int h = blockIdx.y, b = blockIdx.z;
  int bh = b * 12 + h;
  size_t baseQ = ((size_t)b * 2048) * 2304 + h * 64;

  for (int i = 0; i < 4; i++) {
    int chunk = tid + i * 256;
    int row = chunk >> 3, dc = chunk & 7;
    *(bf16x8*)&Qs[row][dc * 8] =
        *(const bf16x8*)&qkv[baseQ + (size_t)(q0 + row) * 2304 + dc * 8];
  }
  __syncthreads();

  bf16x8 qf[2][2];
  for (int i = 0; i < 2; i++)
    for (int s = 0; s < 2; s++)
      qf[i][s] = *(bf16x8*)&Qs[wid * 32 + i * 16 + mr][s * 32 + kq];

  float aa = *ap, ab = *bp, ac = *cp;
  f32x4 o_acc[2][4] = {};
  float l_acc[2][4] = {{0.f, 0.f, 0.f, 0.f}, {0.f, 0.f, 0.f, 0.f}};

  for (int kt = 0; kt < 32; kt++) {
    __syncthreads();  // protect Ks/Vts (+ Ps/Qs) before restaging
    for (int i = 0; i < 2; i++) {
      int chunk = tid + i * 256;
      int row = chunk >> 3, dc = chunk & 7;  // row: 0..63
      *(bf16x8*)&Ks[row][dc * 8] =
          *(const bf16x8*)&qkv[baseQ + (size_t)(kt * 64 + row) * 2304 + 768 + dc * 8];
      *(bf16x8*)&Vts[row][dc * 8] =
          *(const bf16x8*)&vt[((size_t)bh * 64 + row) * 2048 + kt * 64 + dc * 8];
    }
    __syncthreads();  // staging done

    // S = Q K^T, poly, row-sum, P -> LDS (per wave: 32 q-rows x 64 keys)
    for (int i = 0; i < 2; i++) {
      f32x4 sacc[4] = {};
      for (int j = 0; j < 4; j++) {
        for (int s = 0; s < 2; s++) {
          bf16x8 kf = *(bf16x8*)&Ks[j * 16 + mr][s * 32 + kq];
          sacc[j] = __builtin_amdgcn_mfma_f32_16x16x32_bf16(qf[i][s], kf, sacc[j], 0, 0, 0);
        }
      }
      float rs[4] = {0.f, 0.f, 0.f, 0.f};
      for (int j = 0; j < 4; j++) {
        for (int r = 0; r < 4; r++) {
          float S = sacc[j][r] * 0.125f;             // * HEAD_DIM^-0.5
          float p = fmaf(fmaf(aa, S, ab), S, ac);    // a*S^2 + b*S + c
          p = fmaxf(p, 1e-6f);
          rs[r] += p;
          QPs[wid][i * 16 + (lane >> 4) * 4 + r][j * 16 + mr] = (__bf16)p;
        }
      }
      for (int r = 0; r < 4; r++) {
        float v = rs[r];
        v += __shfl_xor(v, 1, 16);
        v += __shfl_xor(v, 2, 16);
        v += __shfl_xor(v, 4, 16);
        v += __shfl_xor(v, 8, 16);
        l_acc[i][r] += v;
      }
    }

    // cross-lane LDS dependency (C-layout writes -> A-layout reads)
    __syncthreads();

    // O += P @ V
    for (int i = 0; i < 2; i++) {
      for (int s = 0; s < 2; s++) {
        bf16x8 pf = *(bf16x8*)&QPs[wid][i * 16 + mr][s * 32 + kq];
        for (int jd = 0; jd < 4; jd++) {
          bf16x8 vf = *(bf16x8*)&Vts[jd * 16 + mr][s * 32 + kq];
          o_acc[i][jd] = __builtin_amdgcn_mfma_f32_16x16x32_bf16(pf, vf, o_acc[i][jd], 0, 0, 0);
        }
      }
    }
  }

  size_t baseO = ((size_t)b * 2048) * 768 + h * 64;
  for (int i = 0; i < 2; i++) {
    for (int r = 0; r < 4; r++) {
      float inv = 1.0f / (l_acc[i][r] + 1e-8f);
      int q = q0 + wid * 32 + i * 16 + (lane >> 4) * 4 + r;
      for (int jd = 0; jd < 4; jd++) {
        int d = jd * 16 + mr;
        outp[baseO + (size_t)q * 768 + d] = (__bf16)(o_acc[i][jd][r] * inv);
      }
    }
  }
}

extern "C" void kernel_launch(void* const* d_in, const int* in_sizes, int n_in,
                              void* d_out, int out_size, void* d_ws, size_t ws_size,
                              hipStream_t stream) {
  const float* x     = (const float*)d_in[0];
  const float* ln1g  = (const float*)d_in[1];
  const float* ln1b  = (const float*)d_in[2];
  const float* ln2g  = (const float*)d_in[3];
  const float* ln2b  = (const float*)d_in[4];
  const float* qkvw  = (const float*)d_in[5];
  const float* qkvb  = (const float*)d_in[6];
  const float* projw = (const float*)d_in[7];
  const float* projb = (const float*)d_in[8];
  const float* fc1w  = (const float*)d_in[9];
  const float* fc1b  = (const float*)d_in[10];
  const float* fc2w  = (const float*)d_in[11];
  const float* fc2b  = (const float*)d_in[12];
  const float* attna = (const float*)d_in[13];
  const float* attnb = (const float*)d_in[14];
  const float* attnc = (const float*)d_in[15];
  const float* gelua = (const float*)d_in[16];
  const float* gelub = (const float*)d_in[17];
  const float* geluc = (const float*)d_in[18];

  char* ws = (char*)d_ws;
  // layout (peak 102,236,160 B), all offsets 16B-aligned:
  __bf16* wT_qkv  = (__bf16*)(ws);             // [2304][768]  3,538,944 B
  __bf16* wT_proj = (__bf16*)(ws + 3538944);   // [768][768]   1,179,648 B
  __bf16* wT_fc1  = (__bf16*)(ws + 4718592);   // [3072][768]  4,718,592 B
  __bf16* wT_fc2  = (__bf16*)(ws + 9437184);   // [768][3072]  4,718,592 B
  __bf16* h       = (__bf16*)(ws + 14155776);  // [8192][768]  bf16 12,582,912 B
  float*  x1      = (float*)(ws + 26738688);   // [8192][768]  f32  25,165,824 B
  __bf16* qkvbuf  = (__bf16*)(ws + 51904512);  // [8192][2304] bf16 37,748,736 B (dead after attn)
  __bf16* u       = (__bf16*)(ws + 51904512);  // [8192][3072] bf16 50,331,648 B (overlaps qkv)
  __bf16* vtbuf   = (__bf16*)(ws + 89653248);  // [3072][2048] bf16 12,582,912 B (live in attn only)
  float*  outp    = (float*)d_out;

  // weight transposes + downcast
  transpose_k<<<dim3(2304 / 32, 768 / 32), 256, 0, stream>>>(qkvw, wT_qkv, 768, 2304);
  transpose_k<<<dim3(768 / 32, 768 / 32), 256, 0, stream>>>(projw, wT_proj, 768, 768);
  transpose_k<<<dim3(3072 / 32, 768 / 32), 256, 0, stream>>>(fc1w, wT_fc1, 768, 3072);
  transpose_k<<<dim3(768 / 32, 3072 / 32), 256, 0, stream>>>(fc2w, wT_fc2, 3072, 768);

  // attention branch
  ln_kernel<<<8192, 256, 0, stream>>>(x, ln1g, ln1b, h);
  gemm128<0><<<dim3(18, 64), 256, 0, stream>>>(h, wT_qkv, qkvb, nullptr, qkvbuf,
                                               8192, 2304, 768, nullptr, nullptr, nullptr);
  transpose_v<<<dim3(64, 2, 48), 256, 0, stream>>>(qkvbuf, vtbuf);
  attn_poly<<<dim3(16, 12, 4), 256, 0, stream>>>(qkvbuf, vtbuf, h, attna, attnb, attnc);
  gemm128<2><<<dim3(6, 64), 256, 0, stream>>>(h, wT_proj, projb, x, x1,
                                              8192, 768, 768, nullptr, nullptr, nullptr);
  // MLP branch
  ln_kernel<<<8192, 256, 0, stream>>>(x1, ln2g, ln2b, h);
  gemm128<1><<<dim3(24, 64), 256, 0, stream>>>(h, wT_fc1, fc1b, nullptr, u,
                                               8192, 3072, 768, gelua, gelub, geluc);
  gemm128<2><<<dim3(6, 64), 256, 0, stream>>>(u, wT_fc2, fc2b, x1, outp,
                                              8192, 768, 3072, nullptr, nullptr, nullptr);
}

// Round 5
// 480.335 us; speedup vs baseline: 1.1419x; 1.0226x over previous
//
#include <hip/hip_runtime.h>

typedef __bf16 bf16x8 __attribute__((ext_vector_type(8)));
typedef __bf16 bf16x4 __attribute__((ext_vector_type(4)));
typedef float f32x4 __attribute__((ext_vector_type(4)));

#define LN_EPS 1e-5f

// async global->LDS, 16B per lane (wave-uniform LDS base + lane*16)
__device__ __forceinline__ void gl2lds16(const void* g, void* l) {
  __builtin_amdgcn_global_load_lds(
      (const __attribute__((address_space(1))) unsigned int*)g,
      (__attribute__((address_space(3))) unsigned int*)l, 16, 0, 0);
}

// -------- weight transpose + downcast: in f32 [R][C] -> out bf16 [C][R] --------
__global__ __launch_bounds__(256) void transpose_k(const float* __restrict__ in,
                                                   __bf16* __restrict__ out,
                                                   int R, int C) {
  __shared__ __bf16 t[32][33];
  int tx = threadIdx.x & 31, ty = threadIdx.x >> 5;  // 32x8
  int c = blockIdx.x * 32 + tx;
  for (int j = 0; j < 4; j++) {
    int r = blockIdx.y * 32 + ty + j * 8;
    t[ty + j * 8][tx] = (__bf16)in[(size_t)r * C + c];
  }
  __syncthreads();
  int r2 = blockIdx.y * 32 + tx;
  for (int j = 0; j < 4; j++) {
    int c2 = blockIdx.x * 32 + ty + j * 8;
    out[(size_t)c2 * R + r2] = t[tx][ty + j * 8];
  }
}

// -------- V transpose: qkv[token][2304] V-part -> vt[(b*12+h)*64+d][2048] --------
__global__ __launch_bounds__(256) void transpose_v(const __bf16* __restrict__ qkv,
                                                   __bf16* __restrict__ vt) {
  __shared__ __bf16 t[32][33];
  int bh = blockIdx.z;
  int b = bh / 12, h = bh % 12;
  int n0 = blockIdx.x * 32, d0 = blockIdx.y * 32;
  int tx = threadIdx.x & 31, ty = threadIdx.x >> 5;
  for (int j = 0; j < 4; j++) {
    int n = n0 + ty + j * 8;
    t[ty + j * 8][tx] = qkv[(size_t)(b * 2048 + n) * 2304 + 1536 + h * 64 + d0 + tx];
  }
  __syncthreads();
  for (int j = 0; j < 4; j++) {
    int d = d0 + ty + j * 8;
    vt[((size_t)bh * 64 + d) * 2048 + n0 + tx] = t[tx][ty + j * 8];
  }
}

// -------- layernorm over 768: f32 in -> bf16 out, one block per row --------
__global__ __launch_bounds__(256) void ln_kernel(const float* __restrict__ x,
                                                 const float* __restrict__ g,
                                                 const float* __restrict__ bta,
                                                 __bf16* __restrict__ out) {
  int row = blockIdx.x;
  size_t base = (size_t)row * 768;
  int t = threadIdx.x;
  float v[3];
  float s = 0.f, s2 = 0.f;
  for (int k = 0; k < 3; k++) {
    float f = x[base + t + k * 256];
    v[k] = f;
    s += f;
    s2 += f * f;
  }
  for (int m = 1; m < 64; m <<= 1) {
    s += __shfl_xor(s, m, 64);
    s2 += __shfl_xor(s2, m, 64);
  }
  __shared__ float sm[4][2];
  int wid = t >> 6, lane = t & 63;
  if (lane == 0) { sm[wid][0] = s; sm[wid][1] = s2; }
  __syncthreads();
  s = sm[0][0] + sm[1][0] + sm[2][0] + sm[3][0];
  s2 = sm[0][1] + sm[1][1] + sm[2][1] + sm[3][1];
  float mu = s * (1.f / 768.f);
  float var = s2 * (1.f / 768.f) - mu * mu;
  float rstd = rsqrtf(var + LN_EPS);
  for (int k = 0; k < 3; k++) {
    int c = t + k * 256;
    out[base + c] = (__bf16)((v[k] - mu) * rstd * g[c] + bta[c]);
  }
}

// -------- MFMA GEMM (m97 structure): C[M,N] = A[M,K] @ BT[N,K]^T + bias --------
template <int EPI>
__global__ __launch_bounds__(256) void gemm128(const __bf16* __restrict__ A,
                                               const __bf16* __restrict__ BT,
                                               const float* __restrict__ bias,
                                               const float* __restrict__ res,
                                               void* __restrict__ outv,
                                               int M, int N, int K,
                                               const float* __restrict__ c0p,
                                               const float* __restrict__ c1p,
                                               const float* __restrict__ c2p) {
  __shared__ __bf16 As[128][32];  // UNPADDED: required by global_load_lds lane mapping
  __shared__ __bf16 Bs[128][32];
  int tid = threadIdx.x;
  int lane = tid & 63, wid = tid >> 6;
  int wr = wid >> 1, wc = wid & 1;  // 2x2 waves of 64x64
  int m0 = blockIdx.y * 128, n0 = blockIdx.x * 128;
  int mr = lane & 15, kq = (lane >> 4) * 8;
  int srow = tid >> 2, scol = (tid & 3) * 8;  // staging: 4 lanes x 16B per row

  f32x4 acc[4][4] = {};

  for (int k0 = 0; k0 < K; k0 += 32) {
    for (int i = 0; i < 2; i++) {
      int row = srow + i * 64;
      gl2lds16(&A[(size_t)(m0 + row) * K + k0 + scol], &As[row][scol]);
      gl2lds16(&BT[(size_t)(n0 + row) * K + k0 + scol], &Bs[row][scol]);
    }
    __syncthreads();
    bf16x8 af[4], bfr[4];
    for (int i = 0; i < 4; i++) af[i] = *(bf16x8*)&As[wr * 64 + i * 16 + mr][kq];
    for (int j = 0; j < 4; j++) bfr[j] = *(bf16x8*)&Bs[wc * 64 + j * 16 + mr][kq];
    for (int i = 0; i < 4; i++)
      for (int j = 0; j < 4; j++)
        acc[i][j] = __builtin_amdgcn_mfma_f32_16x16x32_bf16(af[i], bfr[j], acc[i][j], 0, 0, 0);
    __syncthreads();
  }

  float ga = 0.f, gb = 0.f, gc = 0.f;
  if (EPI == 1) { ga = *c0p; gb = *c1p; gc = *c2p; }

  for (int i = 0; i < 4; i++) {
    for (int j = 0; j < 4; j++) {
      int col = n0 + wc * 64 + j * 16 + mr;
      float bv = bias[col];
      for (int r = 0; r < 4; r++) {
        int row = m0 + wr * 64 + i * 16 + (lane >> 4) * 4 + r;
        size_t idx = (size_t)row * N + col;
        float c = acc[i][j][r] + bv;
        if (EPI == 0) {
          ((__bf16*)outv)[idx] = (__bf16)c;
        } else if (EPI == 1) {
          float u = (ga * c + gb) * c + gc;
          ((__bf16*)outv)[idx] = (__bf16)u;
        } else {
          ((float*)outv)[idx] = c + res[idx];
        }
      }
    }
  }
}

// -------- flash-style polynomial attention, S^T trick --------
// S^T = K*Q^T keeps 4 consecutive keys per lane -> packed b64 P stores into
// Ps[q][key], which is exactly the x32 A-fragment layout for O = P*V.
// qkv: [B*N,2304] bf16 (q|k at cols 0..1535); vt: [(b*12+h)*64+d][2048] bf16
__global__ __launch_bounds__(256, 4) void attn_poly(const __bf16* __restrict__ qkv,
                                                    const __bf16* __restrict__ vt,
                                                    __bf16* __restrict__ outp,
                                                    const float* __restrict__ ap,
                                                    const float* __restrict__ bp,
                                                    const float* __restrict__ cp) {
  // Qs[128][72] aliases Ps[4][32][72]; wave w's Q rows == wave w's Ps region
  __shared__ __bf16 QPs[4][32][72];
  __shared__ __bf16 Ks[64][72];
  __shared__ __bf16 Vts[64][72];
  __bf16(*Qs)[72] = (__bf16(*)[72]) & QPs[0][0][0];

  int tid = threadIdx.x, lane = tid & 63, wid = tid >> 6;
  int mr = lane & 15, quad = lane >> 4, kq = quad * 8;
  int q0 = blockIdx.x * 128;
  int h = blockIdx.y, b = blockIdx.z;
  int bh = b * 12 + h;
  size_t baseQ = ((size_t)b * 2048) * 2304 + h * 64;

  for (int i = 0; i < 4; i++) {
    int chunk = tid + i * 256;
    int row = chunk >> 3, dc = chunk & 7;
    *(bf16x8*)&Qs[row][dc * 8] =
        *(const bf16x8*)&qkv[baseQ + (size_t)(q0 + row) * 2304 + dc * 8];
  }
  __syncthreads();

  bf16x8 qf[2][2];  // B-operand: Q^T[d][q] == Q[q=mr][d=kq..]
  for (int i = 0; i < 2; i++)
    for (int s = 0; s < 2; s++)
      qf[i][s] = *(bf16x8*)&Qs[wid * 32 + i * 16 + mr][s * 32 + kq];

  // fold SCALE=0.125 into poly coefficients: p = a2*raw^2 + b2*raw + c
  float a2 = (*ap) * 0.015625f, b2 = (*bp) * 0.125f, cc = *cp;
  f32x4 o_acc[2][4] = {};
  float l_acc[2] = {0.f, 0.f};

  for (int kt = 0; kt < 32; kt++) {
    __syncthreads();  // A: protect Ks/Vts WAR before restaging
    for (int i = 0; i < 2; i++) {
      int chunk = tid + i * 256;
      int row = chunk >> 3, dc = chunk & 7;  // row: 0..63
      *(bf16x8*)&Ks[row][dc * 8] =
          *(const bf16x8*)&qkv[baseQ + (size_t)(kt * 64 + row) * 2304 + 768 + dc * 8];
      *(bf16x8*)&Vts[row][dc * 8] =
          *(const bf16x8*)&vt[((size_t)bh * 64 + row) * 2048 + kt * 64 + dc * 8];
    }
    __syncthreads();  // B: staging done

    bf16x8 kf[4][2];  // A-operand: K[key=mr][d=kq..]
    for (int j = 0; j < 4; j++)
      for (int s = 0; s < 2; s++)
        kf[j][s] = *(bf16x8*)&Ks[j * 16 + mr][s * 32 + kq];

    // S^T = K*Q^T -> poly -> packed b64 stores of P^T columns (4 keys/lane)
    for (int i = 0; i < 2; i++) {
      f32x4 sacc[4] = {};
      for (int j = 0; j < 4; j++)
        for (int s = 0; s < 2; s++)
          sacc[j] = __builtin_amdgcn_mfma_f32_16x16x32_bf16(kf[j][s], qf[i][s], sacc[j], 0, 0, 0);
      float rsum = 0.f;
      for (int j = 0; j < 4; j++) {
        bf16x4 pk;
        for (int r = 0; r < 4; r++) {
          float S = sacc[j][r];
          float p = fmaf(fmaf(a2, S, b2), S, cc);
          p = fmaxf(p, 1e-6f);
          rsum += p;
          pk[r] = (__bf16)p;
        }
        // P[q = i*16+mr][key = j*16 + quad*4 .. +3]
        *(bf16x4*)&QPs[wid][i * 16 + mr][j * 16 + quad * 4] = pk;
      }
      // per-q (=lane&15) total over this iter's 64 keys: quads hold disjoint key sets
      rsum += __shfl_xor(rsum, 16, 64);
      rsum += __shfl_xor(rsum, 32, 64);
      l_acc[i] += rsum;
    }

    __syncthreads();  // C: cross-lane Ps write->read

    // O = P*V: A = Ps[q][key] (b128), B = V[key][d] via Vts[d][key] (b128)
    for (int i = 0; i < 2; i++) {
      for (int s = 0; s < 2; s++) {
        bf16x8 pf = *(bf16x8*)&QPs[wid][i * 16 + mr][s * 32 + kq];
        for (int dt = 0; dt < 4; dt++) {
          bf16x8 vf = *(bf16x8*)&Vts[dt * 16 + mr][s * 32 + kq];
          o_acc[i][dt] = __builtin_amdgcn_mfma_f32_16x16x32_bf16(pf, vf, o_acc[i][dt], 0, 0, 0);
        }
      }
    }
  }

  // epilogue: O C-layout is [q = quad*4+r][d = mr]; l_acc indexed by q = mr
  size_t baseO = ((size_t)b * 2048) * 768 + h * 64;
  for (int i = 0; i < 2; i++) {
    float inv[4];
    for (int r = 0; r < 4; r++)
      inv[r] = 1.0f / (__shfl(l_acc[i], quad * 4 + r, 64) + 1e-8f);
    for (int dt = 0; dt < 4; dt++) {
      int q = q0 + wid * 32 + i * 16 + quad * 4;
      for (int r = 0; r < 4; r++) {
        outp[baseO + (size_t)(q + r) * 768 + dt * 16 + mr] =
            (__bf16)(o_acc[i][dt][r] * inv[r]);
      }
    }
  }
}

extern "C" void kernel_launch(void* const* d_in, const int* in_sizes, int n_in,
                              void* d_out, int out_size, void* d_ws, size_t ws_size,
                              hipStream_t stream) {
  const float* x     = (const float*)d_in[0];
  const float* ln1g  = (const float*)d_in[1];
  const float* ln1b  = (const float*)d_in[2];
  const float* ln2g  = (const float*)d_in[3];
  const float* ln2b  = (const float*)d_in[4];
  const float* qkvw  = (const float*)d_in[5];
  const float* qkvb  = (const float*)d_in[6];
  const float* projw = (const float*)d_in[7];
  const float* projb = (const float*)d_in[8];
  const float* fc1w  = (const float*)d_in[9];
  const float* fc1b  = (const float*)d_in[10];
  const float* fc2w  = (const float*)d_in[11];
  const float* fc2b  = (const float*)d_in[12];
  const float* attna = (const float*)d_in[13];
  const float* attnb = (const float*)d_in[14];
  const float* attnc = (const float*)d_in[15];
  const float* gelua = (const float*)d_in[16];
  const float* gelub = (const float*)d_in[17];
  const float* geluc = (const float*)d_in[18];

  char* ws = (char*)d_ws;
  __bf16* wT_qkv  = (__bf16*)(ws);             // [2304][768]  3,538,944 B
  __bf16* wT_proj = (__bf16*)(ws + 3538944);   // [768][768]   1,179,648 B
  __bf16* wT_fc1  = (__bf16*)(ws + 4718592);   // [3072][768]  4,718,592 B
  __bf16* wT_fc2  = (__bf16*)(ws + 9437184);   // [768][3072]  4,718,592 B
  __bf16* h       = (__bf16*)(ws + 14155776);  // [8192][768]  bf16 12,582,912 B
  float*  x1      = (float*)(ws + 26738688);   // [8192][768]  f32  25,165,824 B
  __bf16* qkvbuf  = (__bf16*)(ws + 51904512);  // [8192][2304] bf16 (dead after attn)
  __bf16* u       = (__bf16*)(ws + 51904512);  // [8192][3072] bf16 (overlaps qkv)
  __bf16* vtbuf   = (__bf16*)(ws + 89653248);  // [3072][2048] bf16 12,582,912 B
  float*  outp    = (float*)d_out;

  transpose_k<<<dim3(2304 / 32, 768 / 32), 256, 0, stream>>>(qkvw, wT_qkv, 768, 2304);
  transpose_k<<<dim3(768 / 32, 768 / 32), 256, 0, stream>>>(projw, wT_proj, 768, 768);
  transpose_k<<<dim3(3072 / 32, 768 / 32), 256, 0, stream>>>(fc1w, wT_fc1, 768, 3072);
  transpose_k<<<dim3(768 / 32, 3072 / 32), 256, 0, stream>>>(fc2w, wT_fc2, 3072, 768);

  ln_kernel<<<8192, 256, 0, stream>>>(x, ln1g, ln1b, h);
  gemm128<0><<<dim3(18, 64), 256, 0, stream>>>(h, wT_qkv, qkvb, nullptr, qkvbuf,
                                               8192, 2304, 768, nullptr, nullptr, nullptr);
  transpose_v<<<dim3(64, 2, 48), 256, 0, stream>>>(qkvbuf, vtbuf);
  attn_poly<<<dim3(16, 12, 4), 256, 0, stream>>>(qkvbuf, vtbuf, h, attna, attnb, attnc);
  gemm128<2><<<dim3(6, 64), 256, 0, stream>>>(h, wT_proj, projb, x, x1,
                                              8192, 768, 768, nullptr, nullptr, nullptr);
  ln_kernel<<<8192, 256, 0, stream>>>(x1, ln2g, ln2b, h);
  gemm128<1><<<dim3(24, 64), 256, 0, stream>>>(h, wT_fc1, fc1b, nullptr, u,
                                               8192, 3072, 768, gelua, gelub, geluc);
  gemm128<2><<<dim3(6, 64), 256, 0, stream>>>(u, wT_fc2, fc2b, x1, outp,
                                              8192, 768, 3072, nullptr, nullptr, nullptr);
}